// Round 1
// baseline (13997.729 us; speedup 1.0000x reference)
//
#include <hip/hip_runtime.h>
#include <math.h>

#define DIM     1024
#define S_LEN   2048
#define BATCH   2
#define NTOK    4096      // BATCH*S_LEN
#define NHEADS  16
#define NKVH    4
#define HD      64
#define NEXP    8
#define HIDDEN  2816
#define VOCABSZ 32000
#define RMSEPS  1e-6f

// padded MoE segment capacity: 8192 rows + 8*63 pad, rounded to 64 -> 8704
#define MOE_ROWS 8704

// ---------------------------------------------------------------------------
// embedding gather
__global__ void embed_k(const int* __restrict__ tokens, const float* __restrict__ emb,
                        float* __restrict__ h) {
    int t = blockIdx.x;
    int tok = tokens[t];
    const float* er = emb + (long)tok * DIM;
    float* hr = h + (long)t * DIM;
    for (int d = threadIdx.x; d < DIM; d += 256) hr[d] = er[d];
}

// ---------------------------------------------------------------------------
// rmsnorm: one block per token
__global__ void rmsnorm_k(const float* __restrict__ x, const float* __restrict__ w,
                          float* __restrict__ o) {
    int t = blockIdx.x;
    const float* xr = x + (long)t * DIM;
    float ss = 0.f;
    for (int d = threadIdx.x; d < DIM; d += 256) { float v = xr[d]; ss += v * v; }
    __shared__ float red[256];
    red[threadIdx.x] = ss;
    __syncthreads();
    for (int s = 128; s > 0; s >>= 1) {
        if (threadIdx.x < s) red[threadIdx.x] += red[threadIdx.x + s];
        __syncthreads();
    }
    float scale = rsqrtf(red[0] / (float)DIM + RMSEPS);
    float* orow = o + (long)t * DIM;
    for (int d = threadIdx.x; d < DIM; d += 256) orow[d] = xr[d] * scale * w[d];
}

// ---------------------------------------------------------------------------
// RoPE in-place. x layout [t][nheads][64]; pair index i in 0..31
__global__ void rope_k(float* __restrict__ x, int hshift, const int* __restrict__ sposp,
                       int total) {
    int idx = blockIdx.x * 256 + threadIdx.x;
    if (idx >= total) return;
    int i  = idx & 31;
    int th = idx >> 5;                   // t*nheads + h
    int t  = th >> hshift;
    int s  = t & (S_LEN - 1);
    int pos = s + sposp[0];
    // inv = 1 / theta^(2i/64);  log2(10000) = 13.28771238f
    float inv = exp2f(-((float)i / 32.f) * 13.28771238f);
    float ang = (float)pos * inv;
    float c = cosf(ang), sn = sinf(ang);
    float* p = x + ((long)th << 6) + 2 * i;
    float x1 = p[0], x2 = p[1];
    p[0] = x1 * c - x2 * sn;
    p[1] = x1 * sn + x2 * c;
}

// ---------------------------------------------------------------------------
// flash attention, one wave per query row. grid = (BATCH*NHEADS, S_LEN/4), block 256
__global__ __launch_bounds__(256) void attn_k(const float* __restrict__ q,
                                              const float* __restrict__ k,
                                              const float* __restrict__ v,
                                              float* __restrict__ o) {
    int bh = blockIdx.x;
    int b = bh >> 4, h = bh & 15;
    int hkv = h >> 2;
    int w = threadIdx.x >> 6;
    int lane = threadIdx.x & 63;
    int sq = blockIdx.y * 4 + w;

    __shared__ float qs[4][64];
    qs[w][lane] = q[((long)(b * S_LEN + sq) * NHEADS + h) * HD + lane];
    __syncthreads();   // single barrier; all waves reach exactly once

    float m = -1e30f, l = 0.f, acc = 0.f;   // acc holds o[lane]
    int ntile = (sq >> 6) + 1;
    const float scale = 0.125f;             // 1/sqrt(64)

    for (int kt = 0; kt < ntile; ++kt) {
        int kpos = kt * 64 + lane;
        const float* krow = k + ((long)(b * S_LEN + kpos) * NKVH + hkv) * HD;
        float s = 0.f;
#pragma unroll
        for (int d4 = 0; d4 < 16; ++d4) {
            float4 kv4 = *(const float4*)(krow + d4 * 4);
            float4 q4  = *(const float4*)&qs[w][d4 * 4];
            s += kv4.x * q4.x + kv4.y * q4.y + kv4.z * q4.z + kv4.w * q4.w;
        }
        s *= scale;
        if (kpos > sq) s = -1e30f;
        float mt = s;
#pragma unroll
        for (int off = 32; off > 0; off >>= 1) mt = fmaxf(mt, __shfl_xor(mt, off));
        float mnew = fmaxf(m, mt);
        float p = expf(s - mnew);
        float corr = expf(m - mnew);
        float psum = p;
#pragma unroll
        for (int off = 32; off > 0; off >>= 1) psum += __shfl_xor(psum, off);
        l = l * corr + psum;
        m = mnew;
        acc *= corr;
        const float* vbase = v + ((long)(b * S_LEN + kt * 64) * NKVH + hkv) * HD + lane;
#pragma unroll 8
        for (int j = 0; j < 64; ++j) {
            float pj = __shfl(p, j);
            acc += pj * vbase[(long)j * (NKVH * HD)];
        }
    }
    o[((long)(b * S_LEN + sq) * NHEADS + h) * HD + lane] = acc / l;
}

// ---------------------------------------------------------------------------
// gate: logits = xn @ gate_w (1024x8), softmax, top-2, renormalize
__global__ void gate_k(const float* __restrict__ xn, const float* __restrict__ gw,
                       int* __restrict__ tke, float* __restrict__ tkw,
                       int* __restrict__ cnt) {
    int t = blockIdx.x;
    __shared__ float pl[256];
    __shared__ float lg[8];
    int e = threadIdx.x & 7, c = threadIdx.x >> 3;
    const float* xr = xn + (long)t * DIM;
    float s = 0.f;
    for (int i = 0; i < DIM / 32; ++i) {
        int d = c + i * 32;
        s += xr[d] * gw[d * 8 + e];
    }
    pl[threadIdx.x] = s;
    __syncthreads();
    if (threadIdx.x < 8) {
        float sum = 0.f;
        for (int c2 = 0; c2 < 32; ++c2) sum += pl[c2 * 8 + threadIdx.x];
        lg[threadIdx.x] = sum;
    }
    __syncthreads();
    if (threadIdx.x == 0) {
        float mx = lg[0];
        for (int i = 1; i < 8; ++i) mx = fmaxf(mx, lg[i]);
        float pe[8];
        for (int i = 0; i < 8; ++i) pe[i] = expf(lg[i] - mx);
        int i0 = 0;
        for (int i = 1; i < 8; ++i) if (pe[i] > pe[i0]) i0 = i;
        int i1 = -1;
        for (int i = 0; i < 8; ++i) {
            if (i == i0) continue;
            if (i1 < 0 || pe[i] > pe[i1]) i1 = i;
        }
        float w0 = pe[i0], w1 = pe[i1];
        float wsum = w0 + w1;
        w0 /= wsum; w1 /= wsum;
        tke[2 * t] = i0; tke[2 * t + 1] = i1;
        tkw[2 * t] = w0; tkw[2 * t + 1] = w1;
        atomicAdd(&cnt[i0], 1);
        atomicAdd(&cnt[i1], 1);
    }
}

// padded prefix sums of expert counts
__global__ void offs_k(const int* __restrict__ cnt, int* __restrict__ offs) {
    if (threadIdx.x == 0) {
        int o = 0;
        for (int e = 0; e < NEXP; ++e) { offs[e] = o; o += (cnt[e] + 63) & ~63; }
        offs[NEXP] = o;
    }
}

// per-token slot assignment
__global__ void fill_k(const int* __restrict__ tke, const float* __restrict__ tkw,
                       const int* __restrict__ offs, int* __restrict__ fillc,
                       int* __restrict__ rowidx, int* __restrict__ tslot) {
    int t = blockIdx.x * 256 + threadIdx.x;
    if (t >= NTOK) return;
    for (int kk = 0; kk < 2; ++kk) {
        int e = tke[2 * t + kk];
        int pos = atomicAdd(&fillc[e], 1);
        int slot = offs[e] + pos;
        rowidx[slot] = t;
        tslot[2 * t + kk] = slot;
    }
}

// h[t] += w0*eout[s0] + w1*eout[s1]
__global__ void combine_k(const int* __restrict__ tslot, const float* __restrict__ tkw,
                          const float* __restrict__ eout, float* __restrict__ h) {
    int t = blockIdx.x;
    int s0 = tslot[2 * t], s1 = tslot[2 * t + 1];
    float w0 = tkw[2 * t], w1 = tkw[2 * t + 1];
    float* hr = h + (long)t * DIM;
    const float* e0 = eout + (long)s0 * DIM;
    const float* e1 = eout + (long)s1 * DIM;
    for (int d = threadIdx.x; d < DIM; d += 256)
        hr[d] += w0 * e0[d] + w1 * e1[d];
}

// ---------------------------------------------------------------------------
// tiled fp32 GEMM, 64x64 tile, TK=16, 256 threads, 4x4 per thread.
// MODE 0: C = A@B          (plain)
// MODE 1: C += A@B         (residual)
// MODE 2: C = silu(A@B)*(A@B2), A rows gathered via rowidx, expert-segmented
// MODE 3: C = A@B, A rows contiguous (hh), expert-segmented B, store valid rows
template <int MODE>
__global__ __launch_bounds__(256) void gemm_k(
    const float* __restrict__ A, const float* __restrict__ B,
    const float* __restrict__ B2, float* __restrict__ C,
    int M, int N, int K, int lda,
    const int* __restrict__ offs, const int* __restrict__ cnt,
    const int* __restrict__ rowidx) {
    __shared__ float As[16][68];
    __shared__ float Bs[16][68];
    __shared__ float Bs2[16][68];

    int n0 = blockIdx.x * 64, m0 = blockIdx.y * 64;
    int vr = 64;
    const float* Bp = B;
    const float* B2p = B2;
    if (MODE >= 2) {
        int e = -1;
#pragma unroll
        for (int i = 0; i < NEXP; ++i)
            if (m0 >= offs[i] && m0 < offs[i + 1]) e = i;
        if (e < 0) return;
        vr = offs[e] + cnt[e] - m0;
        if (vr <= 0) return;
        if (vr > 64) vr = 64;
        long bs = (long)K * N;
        Bp = B + (long)e * bs;
        if (MODE == 2) B2p = B2 + (long)e * bs;
    }

    int tid = threadIdx.x;
    int tx = tid & 15, ty = tid >> 4;
    float acc[4][4] = {{0.f}};
    float acc2[4][4] = {{0.f}};

    int arow = tid >> 2;    // 0..63
    int kq = tid & 3;
    long aoff;
    if (MODE == 2) {
        int g = (arow < vr) ? rowidx[m0 + arow] : 0;
        aoff = (long)g * lda;
    } else {
        aoff = (long)(m0 + arow) * lda;
    }
    int bkk = tid >> 4, bnq = tid & 15;

    for (int k0 = 0; k0 < K; k0 += 16) {
        float4 av = *(const float4*)(A + aoff + k0 + kq * 4);
        float4 bv = *(const float4*)(Bp + (long)(k0 + bkk) * N + n0 + bnq * 4);
        float4 bv2 = make_float4(0.f, 0.f, 0.f, 0.f);
        if (MODE == 2)
            bv2 = *(const float4*)(B2p + (long)(k0 + bkk) * N + n0 + bnq * 4);
        __syncthreads();
        As[kq * 4 + 0][arow] = av.x;
        As[kq * 4 + 1][arow] = av.y;
        As[kq * 4 + 2][arow] = av.z;
        As[kq * 4 + 3][arow] = av.w;
        *(float4*)&Bs[bkk][bnq * 4] = bv;
        if (MODE == 2) *(float4*)&Bs2[bkk][bnq * 4] = bv2;
        __syncthreads();
#pragma unroll
        for (int kk = 0; kk < 16; ++kk) {
            float4 a4 = *(const float4*)&As[kk][ty * 4];
            float4 b4 = *(const float4*)&Bs[kk][tx * 4];
            float aa[4] = {a4.x, a4.y, a4.z, a4.w};
            float bb[4] = {b4.x, b4.y, b4.z, b4.w};
#pragma unroll
            for (int i = 0; i < 4; ++i)
#pragma unroll
                for (int j = 0; j < 4; ++j) acc[i][j] += aa[i] * bb[j];
            if (MODE == 2) {
                float4 c4 = *(const float4*)&Bs2[kk][tx * 4];
                float cc[4] = {c4.x, c4.y, c4.z, c4.w};
#pragma unroll
                for (int i = 0; i < 4; ++i)
#pragma unroll
                    for (int j = 0; j < 4; ++j) acc2[i][j] += aa[i] * cc[j];
            }
        }
    }

#pragma unroll
    for (int i = 0; i < 4; ++i) {
        int r = ty * 4 + i;
        if (MODE >= 2 && r >= vr) continue;
        float* cp = C + (long)(m0 + r) * N + n0 + tx * 4;
        if (MODE == 0 || MODE == 3) {
            *(float4*)cp = make_float4(acc[i][0], acc[i][1], acc[i][2], acc[i][3]);
        } else if (MODE == 1) {
            float4 old = *(const float4*)cp;
            *(float4*)cp = make_float4(old.x + acc[i][0], old.y + acc[i][1],
                                       old.z + acc[i][2], old.w + acc[i][3]);
        } else {  // MODE 2: silu(acc)*acc2
            float vals[4];
#pragma unroll
            for (int j = 0; j < 4; ++j) {
                float x = acc[i][j];
                vals[j] = x / (1.f + expf(-x)) * acc2[i][j];
            }
            *(float4*)cp = make_float4(vals[0], vals[1], vals[2], vals[3]);
        }
    }
}

// ---------------------------------------------------------------------------
extern "C" void kernel_launch(void* const* d_in, const int* in_sizes, int n_in,
                              void* d_out, int out_size, void* d_ws, size_t ws_size,
                              hipStream_t stream) {
    const int*   tokens = (const int*)d_in[0];
    const int*   sposp  = (const int*)d_in[1];
    const float* emb    = (const float*)d_in[2];
    const float* anw    = (const float*)d_in[3];
    const float* wq     = (const float*)d_in[4];
    const float* wk     = (const float*)d_in[5];
    const float* wv     = (const float*)d_in[6];
    const float* wo     = (const float*)d_in[7];
    const float* fnw    = (const float*)d_in[8];
    const float* gw     = (const float*)d_in[9];
    const float* w1     = (const float*)d_in[10];
    const float* w2     = (const float*)d_in[11];
    const float* w3     = (const float*)d_in[12];
    const float* nw     = (const float*)d_in[13];
    const float* ow     = (const float*)d_in[14];
    float* out = (float*)d_out;

    char* wsb = (char*)d_ws;
    float* h  = (float*)wsb;                 wsb += (long)NTOK * DIM * 4;
    float* xn = (float*)wsb;                 wsb += (long)NTOK * DIM * 4;
    float* q  = (float*)wsb;                 wsb += (long)NTOK * DIM * 4;
    float* kb = (float*)wsb;                 wsb += (long)NTOK * NKVH * HD * 4;
    float* vb = (float*)wsb;                 wsb += (long)NTOK * NKVH * HD * 4;
    float* ao = (float*)wsb;                 wsb += (long)NTOK * DIM * 4;
    float* tkw = (float*)wsb;                wsb += (long)NTOK * 2 * 4;
    int* tke    = (int*)wsb;                 wsb += (long)NTOK * 2 * 4;
    int* tslot  = (int*)wsb;                 wsb += (long)NTOK * 2 * 4;
    int* rowidx = (int*)wsb;                 wsb += (long)MOE_ROWS * 4;
    int* cnt    = (int*)wsb;                 wsb += 8 * 4;
    int* fillc  = (int*)wsb;                 wsb += 8 * 4;
    int* offs   = (int*)wsb;                 wsb += 16 * 4;

    // big MoE scratch lives in d_out (fully overwritten by final logits GEMM)
    float* hh   = out;                                 // MOE_ROWS x HIDDEN
    float* eout = out + (long)MOE_ROWS * HIDDEN;       // MOE_ROWS x DIM

    embed_k<<<NTOK, 256, 0, stream>>>(tokens, emb, h);

    for (int l = 0; l < 2; ++l) {
        const float* wq_l = wq + (long)l * DIM * DIM;
        const float* wk_l = wk + (long)l * DIM * (NKVH * HD);
        const float* wv_l = wv + (long)l * DIM * (NKVH * HD);
        const float* wo_l = wo + (long)l * DIM * DIM;
        const float* gw_l = gw + (long)l * DIM * NEXP;
        const float* w1_l = w1 + (long)l * NEXP * DIM * HIDDEN;
        const float* w2_l = w2 + (long)l * NEXP * HIDDEN * DIM;
        const float* w3_l = w3 + (long)l * NEXP * DIM * HIDDEN;

        // attention
        rmsnorm_k<<<NTOK, 256, 0, stream>>>(h, anw + l * DIM, xn);
        gemm_k<0><<<dim3(DIM / 64, NTOK / 64), 256, 0, stream>>>(
            xn, wq_l, nullptr, q, NTOK, DIM, DIM, DIM, nullptr, nullptr, nullptr);
        gemm_k<0><<<dim3((NKVH * HD) / 64, NTOK / 64), 256, 0, stream>>>(
            xn, wk_l, nullptr, kb, NTOK, NKVH * HD, DIM, DIM, nullptr, nullptr, nullptr);
        gemm_k<0><<<dim3((NKVH * HD) / 64, NTOK / 64), 256, 0, stream>>>(
            xn, wv_l, nullptr, vb, NTOK, NKVH * HD, DIM, DIM, nullptr, nullptr, nullptr);
        rope_k<<<(NTOK * NHEADS * 32) / 256, 256, 0, stream>>>(q, 4, sposp, NTOK * NHEADS * 32);
        rope_k<<<(NTOK * NKVH * 32) / 256, 256, 0, stream>>>(kb, 2, sposp, NTOK * NKVH * 32);
        attn_k<<<dim3(BATCH * NHEADS, S_LEN / 4), 256, 0, stream>>>(q, kb, vb, ao);
        gemm_k<1><<<dim3(DIM / 64, NTOK / 64), 256, 0, stream>>>(
            ao, wo_l, nullptr, h, NTOK, DIM, DIM, DIM, nullptr, nullptr, nullptr);

        // MoE
        rmsnorm_k<<<NTOK, 256, 0, stream>>>(h, fnw + l * DIM, xn);
        hipMemsetAsync(cnt, 0, 16 * sizeof(int), stream);  // cnt + fillc
        gate_k<<<NTOK, 256, 0, stream>>>(xn, gw_l, tke, tkw, cnt);
        offs_k<<<1, 64, 0, stream>>>(cnt, offs);
        fill_k<<<NTOK / 256, 256, 0, stream>>>(tke, tkw, offs, fillc, rowidx, tslot);
        gemm_k<2><<<dim3(HIDDEN / 64, MOE_ROWS / 64), 256, 0, stream>>>(
            xn, w1_l, w3_l, hh, MOE_ROWS, HIDDEN, DIM, DIM, offs, cnt, rowidx);
        gemm_k<3><<<dim3(DIM / 64, MOE_ROWS / 64), 256, 0, stream>>>(
            hh, w2_l, nullptr, eout, MOE_ROWS, DIM, HIDDEN, HIDDEN, offs, cnt, nullptr);
        combine_k<<<NTOK, 256, 0, stream>>>(tslot, tkw, eout, h);
    }

    // final norm + logits
    rmsnorm_k<<<NTOK, 256, 0, stream>>>(h, nw, xn);
    gemm_k<0><<<dim3(VOCABSZ / 64, NTOK / 64), 256, 0, stream>>>(
        xn, ow, nullptr, out, NTOK, VOCABSZ, DIM, DIM, nullptr, nullptr, nullptr);
}